// Round 1
// baseline (847.820 us; speedup 1.0000x reference)
//
#include <hip/hip_runtime.h>

#define NPTS   25600
#define NB     16
#define NRES   320
#define OS     400

// BETA = pi * sqrt((4/1.25*0.75)^2 - 0.8) = pi*sqrt(4.96)
#define BETA_F (3.14159265358979f * 2.22710574513201f)

__device__ __forceinline__ float bessel_i0f(float x) {
    float ax = fabsf(x);
    if (ax < 3.75f) {
        float t = (ax * ax) * (1.0f / 14.0625f);
        return 1.0f + t * (3.5156229f + t * (3.0899424f + t * (1.2067492f +
                     t * (0.2659732f + t * (0.0360768f + t * 0.0045813f)))));
    } else {
        float t = 3.75f / ax;
        return (expf(ax) * rsqrtf(ax)) *
               (0.39894228f + t * (0.01328592f + t * (0.00225319f + t * (-0.00157565f +
                t * (0.00916281f + t * (-0.02057706f + t * (0.02635537f +
                t * (-0.01647633f + t * 0.00392377f))))))));
    }
}

// ---------------------------------------------------------------------------
// Kernel 1: bilinear sample of k-space at trajectory points + Kaiser-Bessel
// scatter onto the 400x400 oversampled grid (complex, float2), via atomics.
// One thread per (m, b): b = tid&15 so the 16 lanes sharing m hit distinct
// batch planes (no intra-wave atomic contention).
// ---------------------------------------------------------------------------
__global__ __launch_bounds__(256)
void k_sample_grid(const float* __restrict__ ksp,   // (16,1,320,320,2)
                   const float* __restrict__ traj,  // (25600,2)
                   float* __restrict__ grid)        // (16,400,400,2)
{
    int gid = blockIdx.x * blockDim.x + threadIdx.x;
    if (gid >= NPTS * NB) return;
    int b = gid & 15;
    int m = gid >> 4;

    float tx = traj[2 * m + 0];
    float ty = traj[2 * m + 1];

    // ---- bilinear sample (always in-bounds: px,py in [0,319)) ----
    float px = (tx * (1.0f / 160.0f) + 1.0f) * 0.5f * 319.0f;
    float py = (ty * (1.0f / 160.0f) + 1.0f) * 0.5f * 319.0f;
    float fx0 = floorf(px), fy0 = floorf(py);
    int x0 = (int)fx0, y0 = (int)fy0;
    float wx1 = px - fx0, wy1 = py - fy0;
    float wx0 = 1.0f - wx1, wy0 = 1.0f - wy1;
    x0 = min(max(x0, 0), NRES - 1);
    y0 = min(max(y0, 0), NRES - 1);
    int x1 = min(x0 + 1, NRES - 1);
    int y1 = min(y0 + 1, NRES - 1);

    const float2* base = (const float2*)ksp + (size_t)b * NRES * NRES;
    float2 v00 = base[y0 * NRES + x0];
    float2 v01 = base[y0 * NRES + x1];
    float2 v10 = base[y1 * NRES + x0];
    float2 v11 = base[y1 * NRES + x1];
    float sr = (v00.x * wx0 + v01.x * wx1) * wy0 + (v10.x * wx0 + v11.x * wx1) * wy1;
    float si = (v00.y * wx0 + v01.y * wx1) * wy0 + (v10.y * wx0 + v11.y * wx1) * wy1;

    // ---- Kaiser-Bessel gridding: coord0 = traj[:,0] -> row, coord1 -> col ----
    float c0 = tx * 1.25f + 200.0f;
    float c1 = ty * 1.25f + 200.0f;
    float s0 = ceilf(c0 - 2.0f);
    float s1 = ceilf(c1 - 2.0f);

    float w0[4], w1[4];
    int   i0[4], i1[4];
#pragma unroll
    for (int t = 0; t < 4; t++) {
        float id0 = s0 + (float)t;
        float d0 = (c0 - id0) * 0.5f;
        float t0 = fmaxf(1.0f - d0 * d0, 0.0f);
        w0[t] = bessel_i0f(BETA_F * sqrtf(t0)) * 0.25f;
        i0[t] = (((int)id0) + OS) % OS;

        float id1 = s1 + (float)t;
        float d1 = (c1 - id1) * 0.5f;
        float t1 = fmaxf(1.0f - d1 * d1, 0.0f);
        w1[t] = bessel_i0f(BETA_F * sqrtf(t1)) * 0.25f;
        i1[t] = (((int)id1) + OS) % OS;
    }

    float* gb = grid + (size_t)b * OS * OS * 2;
#pragma unroll
    for (int t0 = 0; t0 < 4; t0++) {
#pragma unroll
        for (int t1 = 0; t1 < 4; t1++) {
            float w = w0[t0] * w1[t1];
            float* cell = gb + ((size_t)(i0[t0] * OS + i1[t1])) * 2;
            atomicAdd(cell + 0, sr * w);
            atomicAdd(cell + 1, si * w);
        }
    }
}

// ---------------------------------------------------------------------------
// 400-point inverse DFT (positive exponent, unnormalized) as 20x20
// Cooley-Tukey: n = 20*n1+n2, k = 20*k2+k1.
//   S1[k1,n2] = sum_n1 x[20*n1+n2] * E20[n1*k1]        (then * E400[n2*k1])
//   X[20*k2+k1] = sum_n2 S1[k1,n2] * E20[n2*k2]
// LDS index "pos" = k1 + 20*n2 (= k1 + 20*k2 for outputs) -> identity layout.
// ---------------------------------------------------------------------------

// Pass A: row FFTs (along j). 8 rows per block; writes A_t[b][k][i] (64B chunks).
__global__ __launch_bounds__(256)
void k_fft_rows(const float* __restrict__ grid, float* __restrict__ At)
{
    __shared__ float2 E[OS];
    __shared__ float2 In[8 * 401];   // reused as Out
    __shared__ float2 L1[8 * 401];
    int tid = threadIdx.x;
    int b = blockIdx.y;
    int i0 = blockIdx.x * 8;

    for (int t = tid; t < OS; t += 256) {
        float ang = (float)t * 0.015707963267948966f;  // 2*pi/400
        float s, c;
        sincosf(ang, &s, &c);
        E[t] = make_float2(c, s);
    }
    const float2* g = (const float2*)grid + ((size_t)b * OS + i0) * OS;
    for (int o = tid; o < 8 * OS; o += 256) {
        int r = o / OS, j = o - r * OS;
        In[r * 401 + j] = g[r * OS + j];
    }
    __syncthreads();

    // step 1
    for (int o = tid; o < 8 * OS; o += 256) {
        int r = o / OS, pos = o - r * OS;
        int k1 = pos % 20, n2 = pos / 20;
        float sr = 0.0f, si = 0.0f;
        const float2* in = &In[r * 401 + n2];
#pragma unroll
        for (int n1 = 0; n1 < 20; n1++) {
            float2 x = in[20 * n1];
            float2 e = E[(n1 * k1 % 20) * 20];
            sr += x.x * e.x - x.y * e.y;
            si += x.x * e.y + x.y * e.x;
        }
        float2 tw = E[n2 * k1];  // < 400
        L1[r * 401 + pos] = make_float2(sr * tw.x - si * tw.y, sr * tw.y + si * tw.x);
    }
    __syncthreads();

    // step 2 (write into In, which is dead)
    for (int o = tid; o < 8 * OS; o += 256) {
        int r = o / OS, pos = o - r * OS;
        int k1 = pos % 20, k2 = pos / 20;
        float sr = 0.0f, si = 0.0f;
        const float2* l = &L1[r * 401 + k1];
#pragma unroll
        for (int n2 = 0; n2 < 20; n2++) {
            float2 x = l[20 * n2];
            float2 e = E[(n2 * k2 % 20) * 20];
            sr += x.x * e.x - x.y * e.y;
            si += x.x * e.y + x.y * e.x;
        }
        In[r * 401 + pos] = make_float2(sr, si);
    }
    __syncthreads();

    // write transposed: At[b][k][i0+r]
    float2* At2 = (float2*)At;
    for (int o = tid; o < 8 * OS; o += 256) {
        int k = o >> 3, r = o & 7;
        At2[((size_t)b * OS + k) * OS + i0 + r] = In[r * 401 + k];
    }
}

// Pass B: column FFTs (along i), reading contiguous lines of A_t,
// writing X_t[b][v][u] coalesced directly from registers.
__global__ __launch_bounds__(256)
void k_fft_cols(const float* __restrict__ At, float* __restrict__ Xt)
{
    __shared__ float2 E[OS];
    __shared__ float2 In[OS];
    __shared__ float2 L1[OS];
    int tid = threadIdx.x;
    int b = blockIdx.y;
    int v = blockIdx.x;

    for (int t = tid; t < OS; t += 256) {
        float ang = (float)t * 0.015707963267948966f;
        float s, c;
        sincosf(ang, &s, &c);
        E[t] = make_float2(c, s);
    }
    const float2* a = (const float2*)At + ((size_t)b * OS + v) * OS;
    for (int t = tid; t < OS; t += 256) In[t] = a[t];
    __syncthreads();

    for (int pos = tid; pos < OS; pos += 256) {
        int k1 = pos % 20, n2 = pos / 20;
        float sr = 0.0f, si = 0.0f;
#pragma unroll
        for (int n1 = 0; n1 < 20; n1++) {
            float2 x = In[20 * n1 + n2];
            float2 e = E[(n1 * k1 % 20) * 20];
            sr += x.x * e.x - x.y * e.y;
            si += x.x * e.y + x.y * e.x;
        }
        float2 tw = E[n2 * k1];
        L1[pos] = make_float2(sr * tw.x - si * tw.y, sr * tw.y + si * tw.x);
    }
    __syncthreads();

    float2* o2 = (float2*)Xt + ((size_t)b * OS + v) * OS;
    for (int pos = tid; pos < OS; pos += 256) {
        int k1 = pos % 20, k2 = pos / 20;
        float sr = 0.0f, si = 0.0f;
#pragma unroll
        for (int n2 = 0; n2 < 20; n2++) {
            float2 x = L1[k1 + 20 * n2];
            float2 e = E[(n2 * k2 % 20) * 20];
            sr += x.x * e.x - x.y * e.y;
            si += x.x * e.y + x.y * e.x;
        }
        o2[pos] = make_float2(sr, si);
    }
}

// ---------------------------------------------------------------------------
// Pass C: crop (fftshift folded into u=(y+240)%400, v=(x+240)%400, sign
// (-1)^(y+x)), scale 1/320, apodization; LDS 32x32 tile transpose.
// Output layout (16,1,2,320,320).
// ---------------------------------------------------------------------------
__device__ __forceinline__ float apodf(int i) {
    float t = (float)(i - 160) * 0.031415926535897932f;  // pi*4/400
    float a = sqrtf(fmaxf(BETA_F * BETA_F - t * t, 1e-12f));
    return a / sinhf(a);
}

__global__ __launch_bounds__(256)
void k_crop_apod(const float* __restrict__ Xt, float* __restrict__ out)
{
    __shared__ float2 T[32][33];
    int b = blockIdx.z;
    int x0 = blockIdx.x * 32;
    int y0 = blockIdx.y * 32;
    int ul = threadIdx.x & 31;   // u index within tile (load) / x (store)
    int vr = threadIdx.x >> 5;   // 0..7

    const float2* X = (const float2*)Xt + (size_t)b * OS * OS;
#pragma unroll
    for (int it = 0; it < 4; it++) {
        int vi = vr + it * 8;
        int v = (x0 + vi + 240) % OS;
        int u = (y0 + ul + 240) % OS;
        T[vi][ul] = X[v * OS + u];
    }
    __syncthreads();

    int x = x0 + ul;
    float apx = apodf(x);
#pragma unroll
    for (int it = 0; it < 4; it++) {
        int yi = vr + it * 8;
        int y = y0 + yi;
        float2 val = T[ul][yi];
        float s = (((x + y) & 1) ? -1.0f : 1.0f) * (1.0f / 320.0f) * apx * apodf(y);
        out[(((size_t)b * 2 + 0) * NRES + y) * NRES + x] = val.x * s;
        out[(((size_t)b * 2 + 1) * NRES + y) * NRES + x] = val.y * s;
    }
}

extern "C" void kernel_launch(void* const* d_in, const int* in_sizes, int n_in,
                              void* d_out, int out_size, void* d_ws, size_t ws_size,
                              hipStream_t stream) {
    const float* ksp  = (const float*)d_in[0];   // (16,1,320,320,2) f32
    const float* traj = (const float*)d_in[1];   // (25600,2) f32
    float* out = (float*)d_out;                  // (16,1,2,320,320) f32

    const size_t gridElems = (size_t)NB * OS * OS * 2;  // 5,120,000 floats
    float* grid = (float*)d_ws;                   // 20.48 MB; reused as X_t
    float* At   = grid + gridElems;               // 20.48 MB

    hipMemsetAsync(grid, 0, gridElems * sizeof(float), stream);

    k_sample_grid<<<dim3((NPTS * NB) / 256), 256, 0, stream>>>(ksp, traj, grid);
    k_fft_rows  <<<dim3(OS / 8, NB), 256, 0, stream>>>(grid, At);
    k_fft_cols  <<<dim3(OS, NB),     256, 0, stream>>>(At, grid);
    k_crop_apod <<<dim3(10, 10, NB), 256, 0, stream>>>(grid, out);
}

// Round 2
// 233.515 us; speedup vs baseline: 3.6307x; 3.6307x over previous
//
#include <hip/hip_runtime.h>

#define NPTS   25600
#define NB     16
#define NRES   320
#define OS     400
#define NCELL  (OS * OS)      // 160000
#define CAP    16             // ELL slots per cell (Poisson lambda=2.56; overflow list covers tail)
#define MAXOVF 4096

// BETA = pi * sqrt((4/1.25*0.75)^2 - 0.8) = pi*sqrt(4.96)
#define BETA_F (3.14159265358979f * 2.22710574513201f)

__device__ __forceinline__ float bessel_i0f(float x) {
    float ax = fabsf(x);
    if (ax < 3.75f) {
        float t = (ax * ax) * (1.0f / 14.0625f);
        return 1.0f + t * (3.5156229f + t * (3.0899424f + t * (1.2067492f +
                     t * (0.2659732f + t * (0.0360768f + t * 0.0045813f)))));
    } else {
        float t = 3.75f / ax;
        return (expf(ax) * rsqrtf(ax)) *
               (0.39894228f + t * (0.01328592f + t * (0.00225319f + t * (-0.00157565f +
                t * (0.00916281f + t * (-0.02057706f + t * (0.02635537f +
                t * (-0.01647633f + t * 0.00392377f))))))));
    }
}

struct OvfEntry { int cell; int m; float w; float pad; };

// ---------------------------------------------------------------------------
// Kernel B: bilinear sample -> val[m][b] (float2), fully coalesced write.
// ---------------------------------------------------------------------------
__global__ __launch_bounds__(256)
void k_sample(const float* __restrict__ ksp,   // (16,1,320,320,2)
              const float* __restrict__ traj,  // (25600,2)
              float2* __restrict__ val)        // (25600,16)
{
    int gid = blockIdx.x * blockDim.x + threadIdx.x;
    if (gid >= NPTS * NB) return;
    int b = gid & 15;
    int m = gid >> 4;

    float tx = traj[2 * m + 0];
    float ty = traj[2 * m + 1];

    float px = (tx * (1.0f / 160.0f) + 1.0f) * 0.5f * 319.0f;
    float py = (ty * (1.0f / 160.0f) + 1.0f) * 0.5f * 319.0f;
    float fx0 = floorf(px), fy0 = floorf(py);
    int x0 = (int)fx0, y0 = (int)fy0;
    float wx1 = px - fx0, wy1 = py - fy0;
    float wx0 = 1.0f - wx1, wy0 = 1.0f - wy1;
    x0 = min(max(x0, 0), NRES - 1);
    y0 = min(max(y0, 0), NRES - 1);
    int x1 = min(x0 + 1, NRES - 1);
    int y1 = min(y0 + 1, NRES - 1);

    const float2* base = (const float2*)ksp + (size_t)b * NRES * NRES;
    float2 v00 = base[y0 * NRES + x0];
    float2 v01 = base[y0 * NRES + x1];
    float2 v10 = base[y1 * NRES + x0];
    float2 v11 = base[y1 * NRES + x1];
    float sr = (v00.x * wx0 + v01.x * wx1) * wy0 + (v10.x * wx0 + v11.x * wx1) * wy1;
    float si = (v00.y * wx0 + v01.y * wx1) * wy0 + (v10.y * wx0 + v11.y * wx1) * wy1;

    val[gid] = make_float2(sr, si);
}

// ---------------------------------------------------------------------------
// Kernel A: per point, compute the 16 (cell, weight) Kaiser-Bessel taps and
// bin them into a slot-major ELL table: entries[slot*NCELL + cell] = {m, w}.
// ---------------------------------------------------------------------------
__global__ __launch_bounds__(256)
void k_taps(const float* __restrict__ traj,
            int* __restrict__ cursor,          // NCELL counters (zeroed)
            float2* __restrict__ entries,      // CAP * NCELL
            int* __restrict__ ovf_cnt,
            OvfEntry* __restrict__ ovf)
{
    int m = blockIdx.x * blockDim.x + threadIdx.x;
    if (m >= NPTS) return;

    float tx = traj[2 * m + 0];
    float ty = traj[2 * m + 1];
    float c0 = tx * 1.25f + 200.0f;
    float c1 = ty * 1.25f + 200.0f;
    float s0 = ceilf(c0 - 2.0f);
    float s1 = ceilf(c1 - 2.0f);

    float w0[4], w1[4];
    int   i0[4], i1[4];
#pragma unroll
    for (int t = 0; t < 4; t++) {
        float id0 = s0 + (float)t;
        float d0 = (c0 - id0) * 0.5f;
        float t0 = fmaxf(1.0f - d0 * d0, 0.0f);
        w0[t] = bessel_i0f(BETA_F * sqrtf(t0)) * 0.25f;
        i0[t] = (((int)id0) + OS) % OS;

        float id1 = s1 + (float)t;
        float d1 = (c1 - id1) * 0.5f;
        float t1 = fmaxf(1.0f - d1 * d1, 0.0f);
        w1[t] = bessel_i0f(BETA_F * sqrtf(t1)) * 0.25f;
        i1[t] = (((int)id1) + OS) % OS;
    }

#pragma unroll
    for (int t0 = 0; t0 < 4; t0++) {
#pragma unroll
        for (int t1 = 0; t1 < 4; t1++) {
            int cell = i0[t0] * OS + i1[t1];
            float w = w0[t0] * w1[t1];
            int slot = atomicAdd(&cursor[cell], 1);
            if (slot < CAP) {
                entries[slot * NCELL + cell] = make_float2(__int_as_float(m), w);
            } else {
                int oi = atomicAdd(ovf_cnt, 1);
                if (oi < MAXOVF) { ovf[oi].cell = cell; ovf[oi].m = m; ovf[oi].w = w; }
            }
        }
    }
}

// ---------------------------------------------------------------------------
// Kernel D: gather-SpMM. One thread per cell; accumulate all 16 batches in
// registers; plain coalesced stores (covers every cell -> no grid memset).
// ---------------------------------------------------------------------------
__global__ __launch_bounds__(256)
void k_gather(const int* __restrict__ cursor,
              const float2* __restrict__ entries,
              const float2* __restrict__ val,   // (25600,16)
              float2* __restrict__ grid)        // (16,400,400)
{
    int cell = blockIdx.x * blockDim.x + threadIdx.x;
    if (cell >= NCELL) return;
    int cnt = min(cursor[cell], CAP);

    float2 acc[NB];
#pragma unroll
    for (int b = 0; b < NB; b++) acc[b] = make_float2(0.0f, 0.0f);

    for (int k = 0; k < cnt; k++) {
        float2 e = entries[k * NCELL + cell];
        int m = __float_as_int(e.x);
        float w = e.y;
        const float2* v = val + (size_t)m * NB;
#pragma unroll
        for (int b = 0; b < NB; b++) {
            float2 x = v[b];
            acc[b].x += w * x.x;
            acc[b].y += w * x.y;
        }
    }
#pragma unroll
    for (int b = 0; b < NB; b++) {
        grid[(size_t)b * NCELL + cell] = acc[b];
    }
}

// Overflow fixup (normally empty): atomic add after k_gather's plain stores.
__global__ __launch_bounds__(256)
void k_ovf_apply(const int* __restrict__ ovf_cnt,
                 const OvfEntry* __restrict__ ovf,
                 const float2* __restrict__ val,
                 float* __restrict__ grid)
{
    int n = min(*ovf_cnt, MAXOVF);
    for (int i = threadIdx.x; i < n * NB; i += blockDim.x) {
        int oi = i >> 4, b = i & 15;
        int cell = ovf[oi].cell, m = ovf[oi].m;
        float w = ovf[oi].w;
        float2 x = val[(size_t)m * NB + b];
        float* cellp = grid + ((size_t)b * NCELL + cell) * 2;
        atomicAdd(cellp + 0, w * x.x);
        atomicAdd(cellp + 1, w * x.y);
    }
}

// ---------------------------------------------------------------------------
// 400-point inverse DFT as 20x20 Cooley-Tukey (unchanged from R1).
// ---------------------------------------------------------------------------
__global__ __launch_bounds__(256)
void k_fft_rows(const float* __restrict__ grid, float* __restrict__ At)
{
    __shared__ float2 E[OS];
    __shared__ float2 In[8 * 401];
    __shared__ float2 L1[8 * 401];
    int tid = threadIdx.x;
    int b = blockIdx.y;
    int i0 = blockIdx.x * 8;

    for (int t = tid; t < OS; t += 256) {
        float ang = (float)t * 0.015707963267948966f;
        float s, c;
        sincosf(ang, &s, &c);
        E[t] = make_float2(c, s);
    }
    const float2* g = (const float2*)grid + ((size_t)b * OS + i0) * OS;
    for (int o = tid; o < 8 * OS; o += 256) {
        int r = o / OS, j = o - r * OS;
        In[r * 401 + j] = g[r * OS + j];
    }
    __syncthreads();

    for (int o = tid; o < 8 * OS; o += 256) {
        int r = o / OS, pos = o - r * OS;
        int k1 = pos % 20, n2 = pos / 20;
        float sr = 0.0f, si = 0.0f;
        const float2* in = &In[r * 401 + n2];
#pragma unroll
        for (int n1 = 0; n1 < 20; n1++) {
            float2 x = in[20 * n1];
            float2 e = E[(n1 * k1 % 20) * 20];
            sr += x.x * e.x - x.y * e.y;
            si += x.x * e.y + x.y * e.x;
        }
        float2 tw = E[n2 * k1];
        L1[r * 401 + pos] = make_float2(sr * tw.x - si * tw.y, sr * tw.y + si * tw.x);
    }
    __syncthreads();

    for (int o = tid; o < 8 * OS; o += 256) {
        int r = o / OS, pos = o - r * OS;
        int k1 = pos % 20, k2 = pos / 20;
        float sr = 0.0f, si = 0.0f;
        const float2* l = &L1[r * 401 + k1];
#pragma unroll
        for (int n2 = 0; n2 < 20; n2++) {
            float2 x = l[20 * n2];
            float2 e = E[(n2 * k2 % 20) * 20];
            sr += x.x * e.x - x.y * e.y;
            si += x.x * e.y + x.y * e.x;
        }
        In[r * 401 + pos] = make_float2(sr, si);
    }
    __syncthreads();

    float2* At2 = (float2*)At;
    for (int o = tid; o < 8 * OS; o += 256) {
        int k = o >> 3, r = o & 7;
        At2[((size_t)b * OS + k) * OS + i0 + r] = In[r * 401 + k];
    }
}

__global__ __launch_bounds__(256)
void k_fft_cols(const float* __restrict__ At, float* __restrict__ Xt)
{
    __shared__ float2 E[OS];
    __shared__ float2 In[OS];
    __shared__ float2 L1[OS];
    int tid = threadIdx.x;
    int b = blockIdx.y;
    int v = blockIdx.x;

    for (int t = tid; t < OS; t += 256) {
        float ang = (float)t * 0.015707963267948966f;
        float s, c;
        sincosf(ang, &s, &c);
        E[t] = make_float2(c, s);
    }
    const float2* a = (const float2*)At + ((size_t)b * OS + v) * OS;
    for (int t = tid; t < OS; t += 256) In[t] = a[t];
    __syncthreads();

    for (int pos = tid; pos < OS; pos += 256) {
        int k1 = pos % 20, n2 = pos / 20;
        float sr = 0.0f, si = 0.0f;
#pragma unroll
        for (int n1 = 0; n1 < 20; n1++) {
            float2 x = In[20 * n1 + n2];
            float2 e = E[(n1 * k1 % 20) * 20];
            sr += x.x * e.x - x.y * e.y;
            si += x.x * e.y + x.y * e.x;
        }
        float2 tw = E[n2 * k1];
        L1[pos] = make_float2(sr * tw.x - si * tw.y, sr * tw.y + si * tw.x);
    }
    __syncthreads();

    float2* o2 = (float2*)Xt + ((size_t)b * OS + v) * OS;
    for (int pos = tid; pos < OS; pos += 256) {
        int k1 = pos % 20, k2 = pos / 20;
        float sr = 0.0f, si = 0.0f;
#pragma unroll
        for (int n2 = 0; n2 < 20; n2++) {
            float2 x = L1[k1 + 20 * n2];
            float2 e = E[(n2 * k2 % 20) * 20];
            sr += x.x * e.x - x.y * e.y;
            si += x.x * e.y + x.y * e.x;
        }
        o2[pos] = make_float2(sr, si);
    }
}

__device__ __forceinline__ float apodf(int i) {
    float t = (float)(i - 160) * 0.031415926535897932f;
    float a = sqrtf(fmaxf(BETA_F * BETA_F - t * t, 1e-12f));
    return a / sinhf(a);
}

__global__ __launch_bounds__(256)
void k_crop_apod(const float* __restrict__ Xt, float* __restrict__ out)
{
    __shared__ float2 T[32][33];
    int b = blockIdx.z;
    int x0 = blockIdx.x * 32;
    int y0 = blockIdx.y * 32;
    int ul = threadIdx.x & 31;
    int vr = threadIdx.x >> 5;

    const float2* X = (const float2*)Xt + (size_t)b * OS * OS;
#pragma unroll
    for (int it = 0; it < 4; it++) {
        int vi = vr + it * 8;
        int v = (x0 + vi + 240) % OS;
        int u = (y0 + ul + 240) % OS;
        T[vi][ul] = X[v * OS + u];
    }
    __syncthreads();

    int x = x0 + ul;
    float apx = apodf(x);
#pragma unroll
    for (int it = 0; it < 4; it++) {
        int yi = vr + it * 8;
        int y = y0 + yi;
        float2 val = T[ul][yi];
        float s = (((x + y) & 1) ? -1.0f : 1.0f) * (1.0f / 320.0f) * apx * apodf(y);
        out[(((size_t)b * 2 + 0) * NRES + y) * NRES + x] = val.x * s;
        out[(((size_t)b * 2 + 1) * NRES + y) * NRES + x] = val.y * s;
    }
}

extern "C" void kernel_launch(void* const* d_in, const int* in_sizes, int n_in,
                              void* d_out, int out_size, void* d_ws, size_t ws_size,
                              hipStream_t stream) {
    const float* ksp  = (const float*)d_in[0];   // (16,1,320,320,2) f32
    const float* traj = (const float*)d_in[1];   // (25600,2) f32
    float* out = (float*)d_out;                  // (16,1,2,320,320) f32

    // ws layout (floats):
    //   grid    : NB*NCELL*2            = 5,120,000  (20.48 MB)  [reused as Xt]
    //   At      : NB*NCELL*2            = 5,120,000  (20.48 MB)  [aliased: ELL entries, dead before fft_rows]
    //   val     : NPTS*NB*2             =   819,200  ( 3.28 MB)
    //   cursor  : NCELL ints            =   160,000  ( 0.64 MB)
    //   ovf_cnt : 16 ints (pad)
    //   ovf     : MAXOVF * 16 B
    float* grid = (float*)d_ws;
    float* At   = grid + (size_t)NB * NCELL * 2;
    float2* entries = (float2*)At;                       // CAP*NCELL float2 == At size exactly
    float2* val = (float2*)(At + (size_t)NB * NCELL * 2);
    int* cursor  = (int*)(val + (size_t)NPTS * NB);
    int* ovf_cnt = cursor + NCELL;
    OvfEntry* ovf = (OvfEntry*)(ovf_cnt + 16);

    hipMemsetAsync(cursor, 0, (NCELL + 16) * sizeof(int), stream);

    k_sample   <<<dim3((NPTS * NB) / 256), 256, 0, stream>>>(ksp, traj, val);
    k_taps     <<<dim3(NPTS / 256), 256, 0, stream>>>(traj, cursor, entries, ovf_cnt, ovf);
    k_gather   <<<dim3((NCELL + 255) / 256), 256, 0, stream>>>(cursor, entries, val, (float2*)grid);
    k_ovf_apply<<<dim3(1), 256, 0, stream>>>(ovf_cnt, ovf, val, grid);
    k_fft_rows <<<dim3(OS / 8, NB), 256, 0, stream>>>(grid, At);
    k_fft_cols <<<dim3(OS, NB),     256, 0, stream>>>(At, grid);
    k_crop_apod<<<dim3(10, 10, NB), 256, 0, stream>>>(grid, out);
}

// Round 3
// 190.364 us; speedup vs baseline: 4.4537x; 1.2267x over previous
//
#include <hip/hip_runtime.h>

#define NPTS   25600
#define NB     16
#define NRES   320
#define OS     400
#define NCELL  (OS * OS)      // 160000
#define CAP    16
#define MAXOVF 4096
#define LSTR   425            // LDS line stride in float2 (conflict-spreading)

// BETA = pi * sqrt((4/1.25*0.75)^2 - 0.8) = pi*sqrt(4.96)
#define BETA_F (3.14159265358979f * 2.22710574513201f)

__device__ __forceinline__ float bessel_i0f(float x) {
    float ax = fabsf(x);
    if (ax < 3.75f) {
        float t = (ax * ax) * (1.0f / 14.0625f);
        return 1.0f + t * (3.5156229f + t * (3.0899424f + t * (1.2067492f +
                     t * (0.2659732f + t * (0.0360768f + t * 0.0045813f)))));
    } else {
        float t = 3.75f / ax;
        return (expf(ax) * rsqrtf(ax)) *
               (0.39894228f + t * (0.01328592f + t * (0.00225319f + t * (-0.00157565f +
                t * (0.00916281f + t * (-0.02057706f + t * (0.02635537f +
                t * (-0.01647633f + t * 0.00392377f))))))));
    }
}

struct OvfEntry { int cell; int m; float w; float pad; };

// ---------------------------------------------------------------------------
// Bilinear sample -> val[m][b] (float2), coalesced.
// ---------------------------------------------------------------------------
__global__ __launch_bounds__(256)
void k_sample(const float* __restrict__ ksp,
              const float* __restrict__ traj,
              float2* __restrict__ val)
{
    int gid = blockIdx.x * blockDim.x + threadIdx.x;
    if (gid >= NPTS * NB) return;
    int b = gid & 15;
    int m = gid >> 4;

    float tx = traj[2 * m + 0];
    float ty = traj[2 * m + 1];

    float px = (tx * (1.0f / 160.0f) + 1.0f) * 0.5f * 319.0f;
    float py = (ty * (1.0f / 160.0f) + 1.0f) * 0.5f * 319.0f;
    float fx0 = floorf(px), fy0 = floorf(py);
    int x0 = (int)fx0, y0 = (int)fy0;
    float wx1 = px - fx0, wy1 = py - fy0;
    float wx0 = 1.0f - wx1, wy0 = 1.0f - wy1;
    x0 = min(max(x0, 0), NRES - 1);
    y0 = min(max(y0, 0), NRES - 1);
    int x1 = min(x0 + 1, NRES - 1);
    int y1 = min(y0 + 1, NRES - 1);

    const float2* base = (const float2*)ksp + (size_t)b * NRES * NRES;
    float2 v00 = base[y0 * NRES + x0];
    float2 v01 = base[y0 * NRES + x1];
    float2 v10 = base[y1 * NRES + x0];
    float2 v11 = base[y1 * NRES + x1];
    float sr = (v00.x * wx0 + v01.x * wx1) * wy0 + (v10.x * wx0 + v11.x * wx1) * wy1;
    float si = (v00.y * wx0 + v01.y * wx1) * wy0 + (v10.y * wx0 + v11.y * wx1) * wy1;

    val[gid] = make_float2(sr, si);
}

// ---------------------------------------------------------------------------
// Per-point KB taps -> slot-major ELL bins.
// ---------------------------------------------------------------------------
__global__ __launch_bounds__(256)
void k_taps(const float* __restrict__ traj,
            int* __restrict__ cursor,
            float2* __restrict__ entries,
            int* __restrict__ ovf_cnt,
            OvfEntry* __restrict__ ovf)
{
    int m = blockIdx.x * blockDim.x + threadIdx.x;
    if (m >= NPTS) return;

    float tx = traj[2 * m + 0];
    float ty = traj[2 * m + 1];
    float c0 = tx * 1.25f + 200.0f;
    float c1 = ty * 1.25f + 200.0f;
    float s0 = ceilf(c0 - 2.0f);
    float s1 = ceilf(c1 - 2.0f);

    float w0[4], w1[4];
    int   i0[4], i1[4];
#pragma unroll
    for (int t = 0; t < 4; t++) {
        float id0 = s0 + (float)t;
        float d0 = (c0 - id0) * 0.5f;
        float t0 = fmaxf(1.0f - d0 * d0, 0.0f);
        w0[t] = bessel_i0f(BETA_F * sqrtf(t0)) * 0.25f;
        i0[t] = (((int)id0) + OS) % OS;

        float id1 = s1 + (float)t;
        float d1 = (c1 - id1) * 0.5f;
        float t1 = fmaxf(1.0f - d1 * d1, 0.0f);
        w1[t] = bessel_i0f(BETA_F * sqrtf(t1)) * 0.25f;
        i1[t] = (((int)id1) + OS) % OS;
    }

#pragma unroll
    for (int t0 = 0; t0 < 4; t0++) {
#pragma unroll
        for (int t1 = 0; t1 < 4; t1++) {
            int cell = i0[t0] * OS + i1[t1];
            float w = w0[t0] * w1[t1];
            int slot = atomicAdd(&cursor[cell], 1);
            if (slot < CAP) {
                entries[slot * NCELL + cell] = make_float2(__int_as_float(m), w);
            } else {
                int oi = atomicAdd(ovf_cnt, 1);
                if (oi < MAXOVF) { ovf[oi].cell = cell; ovf[oi].m = m; ovf[oi].w = w; }
            }
        }
    }
}

// ---------------------------------------------------------------------------
// Gather-SpMM: one thread per cell, all 16 batches in registers.
// ---------------------------------------------------------------------------
__global__ __launch_bounds__(256)
void k_gather(const int* __restrict__ cursor,
              const float2* __restrict__ entries,
              const float2* __restrict__ val,
              float2* __restrict__ grid)
{
    int cell = blockIdx.x * blockDim.x + threadIdx.x;
    if (cell >= NCELL) return;
    int cnt = min(cursor[cell], CAP);

    float2 acc[NB];
#pragma unroll
    for (int b = 0; b < NB; b++) acc[b] = make_float2(0.0f, 0.0f);

    for (int k = 0; k < cnt; k++) {
        float2 e = entries[k * NCELL + cell];
        int m = __float_as_int(e.x);
        float w = e.y;
        const float2* v = val + (size_t)m * NB;
#pragma unroll
        for (int b = 0; b < NB; b++) {
            float2 x = v[b];
            acc[b].x += w * x.x;
            acc[b].y += w * x.y;
        }
    }
#pragma unroll
    for (int b = 0; b < NB; b++) {
        grid[(size_t)b * NCELL + cell] = acc[b];
    }
}

__global__ __launch_bounds__(256)
void k_ovf_apply(const int* __restrict__ ovf_cnt,
                 const OvfEntry* __restrict__ ovf,
                 const float2* __restrict__ val,
                 float* __restrict__ grid)
{
    int n = min(*ovf_cnt, MAXOVF);
    for (int i = threadIdx.x; i < n * NB; i += blockDim.x) {
        int oi = i >> 4, b = i & 15;
        int cell = ovf[oi].cell, m = ovf[oi].m;
        float w = ovf[oi].w;
        float2 x = val[(size_t)m * NB + b];
        float* cellp = grid + ((size_t)b * NCELL + cell) * 2;
        atomicAdd(cellp + 0, w * x.x);
        atomicAdd(cellp + 1, w * x.y);
    }
}

// ---------------------------------------------------------------------------
// Radix-20 x 20 DFT of a 400-line, register-resident columns, in-place LDS.
// Thread (r, n2) holds x[n2 + 20*n1] in regs; E20 reads are lane-uniform
// broadcasts; W400^{n2*k1} via register recurrence.
// Stage 2 computes only k2 in [0,8)u[12,20) (crop set), compact index.
// ---------------------------------------------------------------------------
__device__ __forceinline__ void dft20_line(float2* S, float2* E20, int tid,
                                           int nlines, bool passA_compact_store)
{
    int r = tid / 20, lane20 = tid % 20;
    bool active = (tid < 240) && (r < nlines);

    float2 x[20];
    if (active) {
        int base = r * LSTR + lane20;
#pragma unroll
        for (int n1 = 0; n1 < 20; n1++) x[n1] = S[base + 20 * n1];
    }
    __syncthreads();

    if (active) {
        int n2 = lane20;
        float ang = (float)n2 * 0.015707963267948966f;  // 2*pi/400
        float sn, cs;
        sincosf(ang, &sn, &cs);
        float2 w = make_float2(cs, sn);                 // W400^n2
        float2 tw = make_float2(1.0f, 0.0f);
        int base = r * LSTR + 21 * n2;
        for (int k1 = 0; k1 < 20; k1++) {
            float sr = 0.0f, si = 0.0f;
            int idx = 0;
#pragma unroll
            for (int n1 = 0; n1 < 20; n1++) {
                float2 e = E20[idx];
                sr += x[n1].x * e.x - x[n1].y * e.y;
                si += x[n1].x * e.y + x[n1].y * e.x;
                idx += k1; if (idx >= 20) idx -= 20;
            }
            S[base + k1] = make_float2(sr * tw.x - si * tw.y, sr * tw.y + si * tw.x);
            float2 nt = make_float2(tw.x * w.x - tw.y * w.y, tw.x * w.y + tw.y * w.x);
            tw = nt;
        }
    }
    __syncthreads();

    float2 y[20];
    if (active) {
        int k1 = lane20;
        int base = r * LSTR + k1;
#pragma unroll
        for (int n2 = 0; n2 < 20; n2++) y[n2] = S[base + 21 * n2];
    }
    __syncthreads();

    if (active) {
        int k1 = lane20;
        int base = r * LSTR;
#pragma unroll
        for (int k2 = 0; k2 < 20; k2++) {
            if (k2 >= 8 && k2 < 12) continue;      // cropped frequencies
            float sr = 0.0f, si = 0.0f;
            int idx = 0;
#pragma unroll
            for (int n2 = 0; n2 < 20; n2++) {
                float2 e = E20[idx];
                sr += y[n2].x * e.x - y[n2].y * e.y;
                si += y[n2].x * e.y + y[n2].y * e.x;
                idx += k2; if (idx >= 20) idx -= 20;
            }
            int v = 20 * k2 + k1;
            int vc = (v < 160) ? v : v - 80;        // compact to [0,320)
            S[base + vc] = make_float2(sr, si);
            (void)passA_compact_store;
        }
    }
    __syncthreads();
}

// Pass A: grid rows (j-axis) -> At[b][vc][i], vc compacted to 320.
__global__ __launch_bounds__(256)
void k_fft_pass_a(const float* __restrict__ grid, float* __restrict__ At)
{
    __shared__ float2 S[12 * LSTR];
    __shared__ float2 E20[20];
    int tid = threadIdx.x;
    int b = blockIdx.y;
    int i0 = blockIdx.x * 12;
    int nlines = min(12, 400 - i0);

    if (tid < 20) {
        float ang = (float)tid * 0.3141592653589793f;  // 2*pi/20
        float sn, cs;
        sincosf(ang, &sn, &cs);
        E20[tid] = make_float2(cs, sn);
    }
    const float2* g = (const float2*)grid + ((size_t)b * OS + i0) * OS;
    for (int o = tid; o < nlines * OS; o += 256) {
        int r = o / OS, j = o - r * OS;
        S[r * LSTR + j] = g[r * OS + j];
    }
    __syncthreads();

    dft20_line(S, E20, tid, nlines, true);

    float2* At2 = (float2*)At;
    for (int o = tid; o < 320 * 12; o += 256) {
        int vc = o / 12, rr = o - vc * 12;
        if (rr < nlines)
            At2[((size_t)b * 320 + vc) * OS + i0 + rr] = S[rr * LSTR + vc];
    }
}

__device__ __forceinline__ float apodf(int i) {
    float t = (float)(i - 160) * 0.031415926535897932f;  // pi*4/400
    float a = sqrtf(fmaxf(BETA_F * BETA_F - t * t, 1e-12f));
    return a / sinhf(a);
}

// Pass B: At lines (i-axis) -> fused crop + fftshift-sign + apod -> out.
__global__ __launch_bounds__(256)
void k_fft_pass_b(const float* __restrict__ At, float* __restrict__ out)
{
    __shared__ float2 S[12 * LSTR];
    __shared__ float2 E20[20];
    __shared__ float apodT[320];
    int tid = threadIdx.x;
    int b = blockIdx.y;
    int vc0 = blockIdx.x * 12;
    int nlines = min(12, 320 - vc0);

    if (tid < 20) {
        float ang = (float)tid * 0.3141592653589793f;
        float sn, cs;
        sincosf(ang, &sn, &cs);
        E20[tid] = make_float2(cs, sn);
    }
    for (int t = tid; t < 320; t += 256) apodT[t] = apodf(t);

    const float2* a = (const float2*)At + ((size_t)b * 320 + vc0) * OS;
    for (int o = tid; o < nlines * OS; o += 256) {
        int r = o / OS, i = o - r * OS;
        S[r * LSTR + i] = a[r * OS + i];
    }
    __syncthreads();

    dft20_line(S, E20, tid, nlines, false);

    // epilogue: uc -> y, line vc -> x; sign (-1)^(x+y), scale, apod.
    for (int o = tid; o < 320 * 12; o += 256) {
        int uc = o / 12, rr = o - uc * 12;
        if (rr >= nlines) continue;
        int y = uc + 160; if (y >= 320) y -= 320;
        int x = vc0 + rr + 160; if (x >= 320) x -= 320;
        float2 v = S[rr * LSTR + uc];
        float sgn = ((x + y) & 1) ? -1.0f : 1.0f;
        float sc = sgn * (1.0f / 320.0f) * apodT[x] * apodT[y];
        out[(((size_t)b * 2 + 0) * NRES + y) * NRES + x] = v.x * sc;
        out[(((size_t)b * 2 + 1) * NRES + y) * NRES + x] = v.y * sc;
    }
}

extern "C" void kernel_launch(void* const* d_in, const int* in_sizes, int n_in,
                              void* d_out, int out_size, void* d_ws, size_t ws_size,
                              hipStream_t stream) {
    const float* ksp  = (const float*)d_in[0];
    const float* traj = (const float*)d_in[1];
    float* out = (float*)d_out;

    // ws layout (floats):
    //   grid    : NB*NCELL*2 (20.48 MB)
    //   entries : CAP*NCELL float2 (20.48 MB)  [aliased: At (16.4 MB), dead after k_gather]
    //   val     : NPTS*NB float2 (3.28 MB)
    //   cursor  : NCELL ints; ovf_cnt; ovf
    float* grid = (float*)d_ws;
    float* At   = grid + (size_t)NB * NCELL * 2;
    float2* entries = (float2*)At;
    float2* val = (float2*)(At + (size_t)NB * NCELL * 2);
    int* cursor  = (int*)(val + (size_t)NPTS * NB);
    int* ovf_cnt = cursor + NCELL;
    OvfEntry* ovf = (OvfEntry*)(ovf_cnt + 16);

    hipMemsetAsync(cursor, 0, (NCELL + 16) * sizeof(int), stream);

    k_sample    <<<dim3((NPTS * NB) / 256), 256, 0, stream>>>(ksp, traj, val);
    k_taps      <<<dim3(NPTS / 256), 256, 0, stream>>>(traj, cursor, entries, ovf_cnt, ovf);
    k_gather    <<<dim3((NCELL + 255) / 256), 256, 0, stream>>>(cursor, entries, val, (float2*)grid);
    k_ovf_apply <<<dim3(1), 256, 0, stream>>>(ovf_cnt, ovf, val, grid);
    k_fft_pass_a<<<dim3(34, NB), 256, 0, stream>>>(grid, At);
    k_fft_pass_b<<<dim3(27, NB), 256, 0, stream>>>(At, out);
}